// Round 14
// baseline (222.671 us; speedup 1.0000x reference)
//
#include <hip/hip_runtime.h>
#include <math.h>

// HardMoE classifier: B=131072, D=1024, E=6, L=2, fp32.
// Skinny-GEMM MFMA design: [B,1024] @ [1024, 18-used-cols] + select.
// r13 FAIL root cause: 6 gate + 12 expert = 18 columns forced into one
// 16-col MFMA tile -> experts 4/5 read zero/wrapped columns (absmax 3.7).
// FIX: TWO 16-col B panels (cols 0-5 gate, 6-17 experts, 18-31 zero),
// two mfma_f32_16x16x32_bf16 per k-step sharing the A fragment.
// Fragment k-permutation cancels (same placement for A and B); C/D layout
// col=lane&15, row=(lane>>4)*4+reg (m89-verified). LDS 64KB -> 2 blocks/CU.
// Near-tie (<0.015, ~4%) fp32-Kahan re-dot from global (validated r10-12).
// LESSON (r2/r8): no min-waves launch_bounds arg.

typedef __attribute__((ext_vector_type(8))) short short8;
typedef __attribute__((ext_vector_type(4))) float f32x4;

static constexpr int En = 6;

template <int CTRL>
__device__ __forceinline__ float dpp_row_add(float v) {
  return v + __int_as_float(__builtin_amdgcn_update_dpp(
                 0, __float_as_int(v), CTRL, 0xf, 0xf, true));
}

__device__ __forceinline__ float wave_sum_bcast(float v) {
  v = dpp_row_add<0x111>(v);
  v = dpp_row_add<0x112>(v);
  v = dpp_row_add<0x114>(v);
  v = dpp_row_add<0x118>(v);
  v = dpp_row_add<0x142>(v);
  v = dpp_row_add<0x143>(v);
  return __int_as_float(__builtin_amdgcn_readlane(__float_as_int(v), 63));
}

__device__ __forceinline__ ushort f2bf(float f) {  // RNE float->bf16
  unsigned u = __float_as_uint(f);
  u += 0x7FFFu + ((u >> 16) & 1u);
  return (ushort)(u >> 16);
}

__global__ __launch_bounds__(512) void hardmoe_mfma(
    const float* __restrict__ cls, const float* __restrict__ gate_w,
    const float* __restrict__ gate_b, const float* __restrict__ expert_w,
    const float* __restrict__ expert_b, float* __restrict__ out) {
  // Two B panels, each: [kc 0..127][col 0..15][k7 0..7] bf16, k = kc*8+k7.
  // Panel p holds global cols p*16 .. p*16+15. 32768 ushort = 64 KB.
  __shared__ ushort ldsB[32768];

  const int tid = threadIdx.x;
  const int lane = tid & 63;
  const int wv = tid >> 6;

  for (int i = tid; i < 32768; i += 512) {
    const int p = i >> 14;
    const int r = i & 16383;
    const int k7 = r & 7, col16 = (r >> 3) & 15, kc = r >> 7;
    const int gcol = p * 16 + col16;
    const int k = kc * 8 + k7;
    float v = 0.f;
    if (gcol < 6) v = gate_w[gcol * 1024 + k];
    else if (gcol < 18) v = expert_w[(gcol - 6) * 1024 + k];
    ldsB[i] = f2bf(v);
  }
  float gb[En];
#pragma unroll
  for (int e = 0; e < En; ++e) gb[e] = gate_b[e];  // uniform -> sgpr
  __syncthreads();

  const int tile = blockIdx.x * 8 + wv;  // 1024 blocks * 8 waves = 8192
  const int g = lane >> 4, cidx = lane & 15;

  // A: row = tile*16 + cidx, k = kk*32 + g*8 + j (same k placement as B).
  const float* arow = cls + (size_t)(tile * 16 + cidx) * 1024 + g * 8;
  const ushort* bbase = ldsB + g * 128 + cidx * 8;

  f32x4 acc0 = {0.f, 0.f, 0.f, 0.f};
  f32x4 acc1 = {0.f, 0.f, 0.f, 0.f};
#pragma unroll 8
  for (int kk = 0; kk < 32; ++kk) {
    const float4 a0 = *(const float4*)(arow + kk * 32);
    const float4 a1 = *(const float4*)(arow + kk * 32 + 4);
    short8 af;
    af[0] = (short)f2bf(a0.x); af[1] = (short)f2bf(a0.y);
    af[2] = (short)f2bf(a0.z); af[3] = (short)f2bf(a0.w);
    af[4] = (short)f2bf(a1.x); af[5] = (short)f2bf(a1.y);
    af[6] = (short)f2bf(a1.z); af[7] = (short)f2bf(a1.w);
    const short8 b0 = *(const short8*)(bbase + kk * 512);
    const short8 b1 = *(const short8*)(bbase + 16384 + kk * 512);
    acc0 = __builtin_amdgcn_mfma_f32_16x16x32_bf16(af, b0, acc0, 0, 0, 0);
    acc1 = __builtin_amdgcn_mfma_f32_16x16x32_bf16(af, b1, acc1, 0, 0, 0);
  }

  // ---- epilogue: acc_p[j] = C[row=g*4+j][col=p*16 + cidx] ----
  float bv[4], sec[4], o0[4], o1[4];
  int be[4];
#pragma unroll
  for (int j = 0; j < 4; ++j) {
    bv[j] = -INFINITY; sec[j] = -INFINITY; be[j] = 0;
#pragma unroll
    for (int e = 0; e < En; ++e) {
      const float v = __shfl(acc0[j], e, 16) + gb[e];
      if (v > bv[j]) {
        sec[j] = bv[j]; bv[j] = v; be[j] = e;
      } else if (v > sec[j]) {
        sec[j] = v;
      }
    }
    // Expert cols: 6+2*be (and +1). be<5 -> panel0; be=5 -> panel1 cols 0,1.
    const int c0 = (6 + 2 * be[j]) & 15;  // be=5: 16&15=0 (panel1)
    const int c1 = (7 + 2 * be[j]) & 15;  // be=5: 17&15=1 (panel1)
    const float x00 = __shfl(acc0[j], c0, 16);
    const float x10 = __shfl(acc1[j], c0, 16);
    const float x01 = __shfl(acc0[j], c1, 16);
    const float x11 = __shfl(acc1[j], c1, 16);
    o0[j] = (be[j] < 5) ? x00 : x10;
    o1[j] = (be[j] < 5) ? x01 : x11;
  }

  // ---- near-tie fallback (~4%): fp32-Kahan gate re-dot from global ----
  unsigned long long need = 0;
#pragma unroll
  for (int j = 0; j < 4; ++j) {
    const unsigned long long m =
        __ballot(cidx == 0 && (bv[j] - sec[j] < 0.015f));
#pragma unroll
    for (int g2 = 0; g2 < 4; ++g2)
      if ((m >> (g2 * 16)) & 1) need |= 1ull << (g2 * 4 + j);
  }

  while (need) {
    const int rr = __ffsll((long long)need) - 1;
    need &= need - 1;
    const int rg = rr >> 2, rj = rr & 3;
    const int row = tile * 16 + rr;
    const float4* crow4 = (const float4*)(cls + (size_t)row * 1024);
    const float4* gw4 = (const float4*)gate_w;
    float kb = -INFINITY;
    int ke = 0;
#pragma unroll
    for (int e = 0; e < En; ++e) {
      float sum = 0.f, comp = 0.f;
#pragma unroll
      for (int t = 0; t < 4; ++t) {
        const float4 cc = crow4[t * 64 + lane];
        const float4 w = gw4[e * 256 + t * 64 + lane];
        const float pr[4] = {cc.x * w.x, cc.y * w.y, cc.z * w.z, cc.w * w.w};
#pragma unroll
        for (int p = 0; p < 4; ++p) {
          const float y = pr[p] - comp;
          const float tt = sum + y;
          comp = (tt - sum) - y;
          sum = tt;
        }
      }
      const float v = wave_sum_bcast(sum) + wave_sum_bcast(comp) + gb[e];
      if (v > kb) { kb = v; ke = e; }
    }
    // Re-select this row's expert outputs from the distributed acc.
    const float aj0 = (rj == 0) ? acc0[0] : (rj == 1) ? acc0[1]
                    : (rj == 2) ? acc0[2] : acc0[3];
    const float aj1 = (rj == 0) ? acc1[0] : (rj == 1) ? acc1[1]
                    : (rj == 2) ? acc1[2] : acc1[3];
    const int ec0 = 6 + 2 * ke;  // 6..16, even
    float n0, n1;
    if (ec0 < 16) {  // wave-uniform branch
      n0 = __int_as_float(
          __builtin_amdgcn_readlane(__float_as_int(aj0), rg * 16 + ec0));
      n1 = __int_as_float(
          __builtin_amdgcn_readlane(__float_as_int(aj0), rg * 16 + ec0 + 1));
    } else {
      n0 = __int_as_float(
          __builtin_amdgcn_readlane(__float_as_int(aj1), rg * 16 + 0));
      n1 = __int_as_float(
          __builtin_amdgcn_readlane(__float_as_int(aj1), rg * 16 + 1));
    }
#pragma unroll
    for (int j = 0; j < 4; ++j) {
      const bool upd = (j == rj) && (g == rg);
      o0[j] = upd ? n0 : o0[j];
      o1[j] = upd ? n1 : o1[j];
      be[j] = upd ? ke : be[j];
    }
  }

  // ---- store: lane g*16+c (c<4) stores row tile*16 + g*4 + c ----
  if (cidx < 4) {
    const float s0 = (cidx == 0) ? o0[0] : (cidx == 1) ? o0[1]
                   : (cidx == 2) ? o0[2] : o0[3];
    const float s1 = (cidx == 0) ? o1[0] : (cidx == 1) ? o1[1]
                   : (cidx == 2) ? o1[2] : o1[3];
    const int sb = (cidx == 0) ? be[0] : (cidx == 1) ? be[1]
                 : (cidx == 2) ? be[2] : be[3];
    const int row = tile * 16 + g * 4 + cidx;
    ((float2*)out)[row] =
        make_float2(s0 + expert_b[sb * 2 + 0], s1 + expert_b[sb * 2 + 1]);
  }
}

extern "C" void kernel_launch(void* const* d_in, const int* in_sizes, int n_in,
                              void* d_out, int out_size, void* d_ws,
                              size_t ws_size, hipStream_t stream) {
  const float* cls = (const float*)d_in[0];
  const float* gate_w = (const float*)d_in[1];
  const float* gate_b = (const float*)d_in[2];
  const float* expert_w = (const float*)d_in[3];
  const float* expert_b = (const float*)d_in[4];
  float* out = (float*)d_out;

  // 1024 blocks * 8 waves = 8192 waves = 8192 16-row tiles (exact).
  hipLaunchKernelGGL(hardmoe_mfma, dim3(1024), dim3(512), 0, stream, cls,
                     gate_w, gate_b, expert_w, expert_b, out);
}

// Round 15
// 169.316 us; speedup vs baseline: 1.3151x; 1.3151x over previous
//
#include <hip/hip_runtime.h>
#include <math.h>

// HardMoE classifier: B=131072, D=1024, E=6, L=2, fp32.
// Skinny-GEMM MFMA: [B,1024] @ [1024,18 used cols] in two 16-col bf16
// panels (cols 0-5 gate, 6-17 expert, rest zero), 2 mfma_16x16x32_bf16
// per k-step sharing the A fragment. r14 = 222us diagnosed as: unroll-8
// VGPR blowup (8 waves/CU), 1024 re-stagings, fat f2bf + Kahan fallback.
// r15: persistent 512 blocks (stage once, 2 tiles/wave), unroll 2
// (VGPR<=128 -> 16 waves/CU), pack2 half-up bf16 A-convert (5 instr/pair),
// plain-fp32 fallback (thr 0.015 ~ 4 sigma of bf16 logit err).
// C/D layout col=lane&15, row=(lane>>4)*4+reg (m89-verified; r14 passed).
// LESSON (r2/r8): no min-waves launch_bounds arg.

typedef __attribute__((ext_vector_type(8))) short short8;
typedef __attribute__((ext_vector_type(4))) float f32x4;
typedef __attribute__((ext_vector_type(4))) unsigned int uint4v;

static constexpr int En = 6;

template <int CTRL>
__device__ __forceinline__ float dpp_row_add(float v) {
  return v + __int_as_float(__builtin_amdgcn_update_dpp(
                 0, __float_as_int(v), CTRL, 0xf, 0xf, true));
}

__device__ __forceinline__ float wave_sum_bcast(float v) {
  v = dpp_row_add<0x111>(v);
  v = dpp_row_add<0x112>(v);
  v = dpp_row_add<0x114>(v);
  v = dpp_row_add<0x118>(v);
  v = dpp_row_add<0x142>(v);
  v = dpp_row_add<0x143>(v);
  return __int_as_float(__builtin_amdgcn_readlane(__float_as_int(v), 63));
}

__device__ __forceinline__ ushort f2bf(float f) {  // RNE float->bf16
  unsigned u = __float_as_uint(f);
  u += 0x7FFFu + ((u >> 16) & 1u);
  return (ushort)(u >> 16);
}

// Pack two floats to packed bf16x2 (round-half-up; ties differ from RNE
// with prob ~2^-16 per element -- covered by the fallback threshold).
__device__ __forceinline__ unsigned pack2(float lo, float hi) {
  const unsigned a = __float_as_uint(lo) + 0x8000u;
  const unsigned b = __float_as_uint(hi) + 0x8000u;
  return (b & 0xFFFF0000u) | (a >> 16);
}

__global__ __launch_bounds__(512) void hardmoe_mfma(
    const float* __restrict__ cls, const float* __restrict__ gate_w,
    const float* __restrict__ gate_b, const float* __restrict__ expert_w,
    const float* __restrict__ expert_b, float* __restrict__ out) {
  // Two B panels: [kc 0..127][col 0..15][k7 0..7] bf16, k = kc*8+k7.
  // Panel p holds global cols p*16..p*16+15. 32768 ushort = 64 KB.
  __shared__ ushort ldsB[32768];

  const int tid = threadIdx.x;
  const int lane = tid & 63;
  const int wv = tid >> 6;

  for (int i = tid; i < 32768; i += 512) {
    const int p = i >> 14;
    const int r = i & 16383;
    const int k7 = r & 7, col16 = (r >> 3) & 15, kc = r >> 7;
    const int gcol = p * 16 + col16;
    const int k = kc * 8 + k7;
    float v = 0.f;
    if (gcol < 6) v = gate_w[gcol * 1024 + k];
    else if (gcol < 18) v = expert_w[(gcol - 6) * 1024 + k];
    ldsB[i] = f2bf(v);
  }
  float gb[En];
#pragma unroll
  for (int e = 0; e < En; ++e) gb[e] = gate_b[e];  // uniform -> sgpr
  __syncthreads();

  const int g = lane >> 4, cidx = lane & 15;
  const ushort* bbase = ldsB + g * 128 + cidx * 8;

  // Persistent: 512 blocks * 8 waves = 4096 waves; tiles 8192 -> 2 each.
  for (int tile = blockIdx.x * 8 + wv; tile < 8192; tile += 4096) {
    // A: row = tile*16 + cidx, k = kk*32 + g*8 + j (same placement as B).
    const float* arow = cls + (size_t)(tile * 16 + cidx) * 1024 + g * 8;

    f32x4 acc0 = {0.f, 0.f, 0.f, 0.f};
    f32x4 acc1 = {0.f, 0.f, 0.f, 0.f};
#pragma unroll 2
    for (int kk = 0; kk < 32; ++kk) {
      const float4 a0 = *(const float4*)(arow + kk * 32);
      const float4 a1 = *(const float4*)(arow + kk * 32 + 4);
      uint4v ap;
      ap.x = pack2(a0.x, a0.y);
      ap.y = pack2(a0.z, a0.w);
      ap.z = pack2(a1.x, a1.y);
      ap.w = pack2(a1.z, a1.w);
      const short8 af = __builtin_bit_cast(short8, ap);
      const short8 b0 = *(const short8*)(bbase + kk * 512);
      const short8 b1 = *(const short8*)(bbase + 16384 + kk * 512);
      acc0 = __builtin_amdgcn_mfma_f32_16x16x32_bf16(af, b0, acc0, 0, 0, 0);
      acc1 = __builtin_amdgcn_mfma_f32_16x16x32_bf16(af, b1, acc1, 0, 0, 0);
    }

    // ---- epilogue: acc_p[j] = C[row=g*4+j][col=p*16+cidx] ----
    float bv[4], sec[4], o0[4], o1[4];
    int be[4];
#pragma unroll
    for (int j = 0; j < 4; ++j) {
      bv[j] = -INFINITY; sec[j] = -INFINITY; be[j] = 0;
#pragma unroll
      for (int e = 0; e < En; ++e) {
        const float v = __shfl(acc0[j], e, 16) + gb[e];
        if (v > bv[j]) {
          sec[j] = bv[j]; bv[j] = v; be[j] = e;
        } else if (v > sec[j]) {
          sec[j] = v;
        }
      }
      // Expert cols 6+2*be, 7+2*be; be=5 wraps to panel1 cols 0,1.
      const int c0 = (6 + 2 * be[j]) & 15;
      const int c1 = (7 + 2 * be[j]) & 15;
      const float x00 = __shfl(acc0[j], c0, 16);
      const float x10 = __shfl(acc1[j], c0, 16);
      const float x01 = __shfl(acc0[j], c1, 16);
      const float x11 = __shfl(acc1[j], c1, 16);
      o0[j] = (be[j] < 5) ? x00 : x10;
      o1[j] = (be[j] < 5) ? x01 : x11;
    }

    // ---- near-tie fallback (~3%): plain fp32 gate re-dot from global ----
    unsigned long long need = 0;
#pragma unroll
    for (int j = 0; j < 4; ++j) {
      const unsigned long long m =
          __ballot(cidx == 0 && (bv[j] - sec[j] < 0.015f));
#pragma unroll
      for (int g2 = 0; g2 < 4; ++g2)
        if ((m >> (g2 * 16)) & 1) need |= 1ull << (g2 * 4 + j);
    }

    while (need) {
      const int rr = __ffsll((long long)need) - 1;
      need &= need - 1;
      const int rg = rr >> 2, rj = rr & 3;
      const int row = tile * 16 + rr;
      const float4* crow4 = (const float4*)(cls + (size_t)row * 1024);
      const float4* gw4 = (const float4*)gate_w;
      float kb = -INFINITY;
      int ke = 0;
#pragma unroll
      for (int e = 0; e < En; ++e) {
        float sum = 0.f;
#pragma unroll
        for (int t = 0; t < 4; ++t) {
          const float4 cc = crow4[t * 64 + lane];
          const float4 w = gw4[e * 256 + t * 64 + lane];
          sum = fmaf(cc.x, w.x, sum);
          sum = fmaf(cc.y, w.y, sum);
          sum = fmaf(cc.z, w.z, sum);
          sum = fmaf(cc.w, w.w, sum);
        }
        const float v = wave_sum_bcast(sum) + gb[e];
        if (v > kb) { kb = v; ke = e; }
      }
      const float aj0 = (rj == 0) ? acc0[0] : (rj == 1) ? acc0[1]
                      : (rj == 2) ? acc0[2] : acc0[3];
      const float aj1 = (rj == 0) ? acc1[0] : (rj == 1) ? acc1[1]
                      : (rj == 2) ? acc1[2] : acc1[3];
      const int ec0 = 6 + 2 * ke;
      float n0, n1;
      if (ec0 < 16) {  // wave-uniform branch
        n0 = __int_as_float(
            __builtin_amdgcn_readlane(__float_as_int(aj0), rg * 16 + ec0));
        n1 = __int_as_float(
            __builtin_amdgcn_readlane(__float_as_int(aj0), rg * 16 + ec0 + 1));
      } else {
        n0 = __int_as_float(
            __builtin_amdgcn_readlane(__float_as_int(aj1), rg * 16 + 0));
        n1 = __int_as_float(
            __builtin_amdgcn_readlane(__float_as_int(aj1), rg * 16 + 1));
      }
#pragma unroll
      for (int j = 0; j < 4; ++j) {
        const bool upd = (j == rj) && (g == rg);
        o0[j] = upd ? n0 : o0[j];
        o1[j] = upd ? n1 : o1[j];
        be[j] = upd ? ke : be[j];
      }
    }

    // ---- store: lane g*16+c (c<4) stores row tile*16 + g*4 + c ----
    if (cidx < 4) {
      const float s0 = (cidx == 0) ? o0[0] : (cidx == 1) ? o0[1]
                     : (cidx == 2) ? o0[2] : o0[3];
      const float s1 = (cidx == 0) ? o1[0] : (cidx == 1) ? o1[1]
                     : (cidx == 2) ? o1[2] : o1[3];
      const int sb = (cidx == 0) ? be[0] : (cidx == 1) ? be[1]
                   : (cidx == 2) ? be[2] : be[3];
      const int row = tile * 16 + g * 4 + cidx;
      ((float2*)out)[row] =
          make_float2(s0 + expert_b[sb * 2 + 0], s1 + expert_b[sb * 2 + 1]);
    }
  }
}

extern "C" void kernel_launch(void* const* d_in, const int* in_sizes, int n_in,
                              void* d_out, int out_size, void* d_ws,
                              size_t ws_size, hipStream_t stream) {
  const float* cls = (const float*)d_in[0];
  const float* gate_w = (const float*)d_in[1];
  const float* gate_b = (const float*)d_in[2];
  const float* expert_w = (const float*)d_in[3];
  const float* expert_b = (const float*)d_in[4];
  float* out = (float*)d_out;

  // Persistent: 512 blocks * 512 threads = 2 blocks/CU; 2 tiles per wave.
  hipLaunchKernelGGL(hardmoe_mfma, dim3(512), dim3(512), 0, stream, cls,
                     gate_w, gate_b, expert_w, expert_b, out);
}